// Round 8
// baseline (113.007 us; speedup 1.0000x reference)
//
#include <hip/hip_runtime.h>
#include <hip/hip_cooperative_groups.h>

namespace cg = cooperative_groups;

#define NCLS 80
#define MAXB 20
#define N0 27648     // 96*96*3
#define N1 110592    // 192*192*3
#define NTOT (N0 + N1)
#define CAP 8192       // per-class candidate capacity in workspace
#define DT 512         // block size
#define NBLK (NTOT / DT)   // 270 blocks (cooperative: <= residency capacity)
#define DSTAGE 3072    // per-block candidate staging (expected ~1120)
#define CNT_STRIDE 16  // pad class counters to one 64B line each
#define NB 256         // score histogram buckets ((bits-0.6f)>>15, max 204)
#define TARGET 128     // top-k cut for fast NMS path
#define SCAP 256       // compact-list capacity (4 slots/lane in wave 0)

__device__ __forceinline__ float sigf(float x) {
    return 1.0f / (1.0f + expf(-x));
}

// ---- DPP wave64 primitives (proven exact rounds 5-7, absmax 0) ----
__device__ __forceinline__ unsigned wave_max_bcast(unsigned x) {
    unsigned t;
    t = (unsigned)__builtin_amdgcn_update_dpp((int)x, (int)x, 0x111, 0xF, 0xF, false); x = x > t ? x : t;
    t = (unsigned)__builtin_amdgcn_update_dpp((int)x, (int)x, 0x112, 0xF, 0xF, false); x = x > t ? x : t;
    t = (unsigned)__builtin_amdgcn_update_dpp((int)x, (int)x, 0x114, 0xF, 0xF, false); x = x > t ? x : t;
    t = (unsigned)__builtin_amdgcn_update_dpp((int)x, (int)x, 0x118, 0xF, 0xF, false); x = x > t ? x : t;
    t = (unsigned)__builtin_amdgcn_update_dpp((int)x, (int)x, 0x142, 0xF, 0xF, false); x = x > t ? x : t;
    t = (unsigned)__builtin_amdgcn_update_dpp((int)x, (int)x, 0x143, 0xF, 0xF, false); x = x > t ? x : t;
    return (unsigned)__builtin_amdgcn_readlane((int)x, 63);
}

__device__ __forceinline__ unsigned wave_min_bcast(unsigned x) {
    unsigned t;
    t = (unsigned)__builtin_amdgcn_update_dpp((int)x, (int)x, 0x111, 0xF, 0xF, false); x = x < t ? x : t;
    t = (unsigned)__builtin_amdgcn_update_dpp((int)x, (int)x, 0x112, 0xF, 0xF, false); x = x < t ? x : t;
    t = (unsigned)__builtin_amdgcn_update_dpp((int)x, (int)x, 0x114, 0xF, 0xF, false); x = x < t ? x : t;
    t = (unsigned)__builtin_amdgcn_update_dpp((int)x, (int)x, 0x118, 0xF, 0xF, false); x = x < t ? x : t;
    t = (unsigned)__builtin_amdgcn_update_dpp((int)x, (int)x, 0x142, 0xF, 0xF, false); x = x < t ? x : t;
    t = (unsigned)__builtin_amdgcn_update_dpp((int)x, (int)x, 0x143, 0xF, 0xF, false); x = x < t ? x : t;
    return (unsigned)__builtin_amdgcn_readlane((int)x, 63);
}

// Wave64 inclusive +scan (LLVM AtomicOptimizer idiom).
__device__ __forceinline__ unsigned wave_incl_scan(unsigned x) {
    x += (unsigned)__builtin_amdgcn_update_dpp(0, (int)x, 0x111, 0xF, 0xF, false);
    x += (unsigned)__builtin_amdgcn_update_dpp(0, (int)x, 0x112, 0xF, 0xF, false);
    x += (unsigned)__builtin_amdgcn_update_dpp(0, (int)x, 0x114, 0xF, 0xF, false);
    x += (unsigned)__builtin_amdgcn_update_dpp(0, (int)x, 0x118, 0xF, 0xF, false);
    x += (unsigned)__builtin_amdgcn_update_dpp(0, (int)x, 0x142, 0xA, 0xF, false);
    x += (unsigned)__builtin_amdgcn_update_dpp(0, (int)x, 0x143, 0xC, 0xF, false);
    return x;
}

// Single cooperative kernel: [zero counts] -> grid.sync -> [decode, proven
// r7 phases] -> grid.sync -> [NMS on blocks 0..79, proven r7 phases].
// LDS overlaid: decode views (29.3KB) and NMS views (15.4KB) share one arena.
__global__ __launch_bounds__(DT) void fused_kernel(
    const float* __restrict__ feats0, const float* __restrict__ feats1,
    float4* __restrict__ boxes, uint2* __restrict__ cands,
    int* __restrict__ counts, float* __restrict__ out)
{
    cg::grid_group grid = cg::this_grid();

    __shared__ __align__(16) char smem[29312];
    __shared__ int s_npass, s_n, s_tau, s_m;

    // decode views
    unsigned* p_gi   = (unsigned*)(smem);              // 2048
    float*    p_conf = (float*)(smem + 2048);          // 2048
    float*    s_esc  = (float*)(smem + 4096);          // 12288
    unsigned* s_ent  = (unsigned*)(smem + 16384);      // 12288
    int*      s_cnt  = (int*)(smem + 28672);           // 320
    int*      s_base = (int*)(smem + 28992);           // 320

    int tid = threadIdx.x;
    int blk = blockIdx.x;

    // ---- stage A: zero global counts (threads 0..1279 across blocks 0-2) ----
    for (int t = blk * DT + tid; t < NCLS * CNT_STRIDE; t += NBLK * DT)
        counts[t] = 0;

    // LDS init (before first barrier)
    if (tid == 0) { s_npass = 0; s_n = 0; }
    for (int c = tid; c < NCLS; c += DT) s_cnt[c] = 0;

    grid.sync();   // counts zeroed + LDS init visible

    // ---- stage B: decode (identical to r7) ----
    const float* feats;
    int S, base, i;
    float aw0, ah0, aw1, ah1, aw2, ah2;
    if (blk < N0 / DT) {
        feats = feats0; S = 96; base = 0;
        i = blk * DT + tid;
        aw0 = 81.0f;  ah0 = 82.0f;  aw1 = 135.0f; ah1 = 169.0f; aw2 = 344.0f; ah2 = 319.0f;
    } else {
        feats = feats1; S = 192; base = N0;
        i = (blk - N0 / DT) * DT + tid;
        aw0 = 23.0f;  ah0 = 27.0f;  aw1 = 37.0f;  ah1 = 58.0f;  aw2 = 81.0f;  ah2 = 82.0f;
    }

    // phase 0: conf gate (only f[4] needed)
    float sconf = sigf(feats[(size_t)i * 85 + 4]);
    if (sconf >= 0.6f) {   // sconf < 0.6 => all class scores < 0.6 (exact)
        int sl = atomicAdd(&s_npass, 1);
        p_gi[sl] = (unsigned)(base + i);
        p_conf[sl] = sconf;
    }
    __syncthreads();

    int npass = s_npass;

    // phase 0b: box decode + write for pass anchors only
    for (int e = tid; e < npass; e += DT) {
        int il = (int)p_gi[e] - base;
        int a = il % 3;
        int cell = il / 3;
        int gx = cell % S;
        int gy = cell / S;
        const float* f = feats + (size_t)il * 85;
        float tx = f[0], ty = f[1], tw = f[2], th = f[3];

        float Sf = (float)S;
        float inpf = Sf * 32.0f;
        float aw = (a == 0) ? aw0 : ((a == 1) ? aw1 : aw2);
        float ah = (a == 0) ? ah0 : ((a == 1) ? ah1 : ah2);

        float x = (sigf(tx) + (float)gx) / Sf;
        float y = (sigf(ty) + (float)gy) / Sf;
        float w = expf(tw) * aw / inpf;
        float h = expf(th) * ah / inpf;

        // yolo_correct_boxes: letterbox constants identical for both layers
        const float OFF = 0.21875f;
        const float SC  = 3072.0f / 1728.0f;
        float yy = (y - OFF) * SC;
        float hh = h * SC;

        boxes[p_gi[e]] = make_float4((yy - hh * 0.5f) * 1080.0f,
                                     (x  - w  * 0.5f) * 1920.0f,
                                     (yy + hh * 0.5f) * 1080.0f,
                                     (x  + w  * 0.5f) * 1920.0f);
    }

    // phase 1: dense (pass-anchor, class) score emission
    int tot = npass * NCLS;
    for (int wk = tid; wk < tot; wk += DT) {
        int sl = wk / NCLS;
        int c  = wk - sl * NCLS;
        float pv = feats[(size_t)(p_gi[sl] - (unsigned)base) * 85 + 5 + c];
        float s = p_conf[sl] * sigf(pv);
        if (s >= 0.6f) {
            int e = atomicAdd(&s_n, 1);
            if (e < DSTAGE) {
                s_esc[e] = s;
                s_ent[e] = p_gi[sl] | ((unsigned)c << 18);
            }
        }
    }
    __syncthreads();

    int n = s_n < DSTAGE ? s_n : DSTAGE;

    // phase 2: per-class block totals
    for (int e = tid; e < n; e += DT)
        atomicAdd(&s_cnt[s_ent[e] >> 18], 1);
    __syncthreads();

    // phase 3: one reserve atomic per (block,class), padded lines
    for (int c = tid; c < NCLS; c += DT) {
        int k = s_cnt[c];
        s_base[c] = (k > 0) ? atomicAdd(&counts[c * CNT_STRIDE], k) : 0;
        s_cnt[c] = 0;
    }
    __syncthreads();

    // phase 4: scatter into reserved slices
    for (int e = tid; e < n; e += DT) {
        unsigned ent = s_ent[e];
        int c = ent >> 18;
        int lpos = atomicAdd(&s_cnt[c], 1);
        int pos = s_base[c] + lpos;
        if (pos < CAP)
            cands[(size_t)c * CAP + pos] =
                make_uint2(__float_as_uint(s_esc[e]), ent & 0x3FFFFu);
    }

    grid.sync();   // all candidates + counts + boxes visible device-wide

    // ---- stage C: NMS, blocks 0..NCLS-1 only (identical to r7, DT threads) ----
    if (blk >= NCLS) return;

    // NMS views (overlay the decode arena)
    float4*   s_cbox = (float4*)(smem);                // 4096
    unsigned* s_csc  = (unsigned*)(smem + 4096);       // 1024
    unsigned* s_cix  = (unsigned*)(smem + 5120);       // 1024
    int*      s_hist = (int*)(smem + 6144);            // 1024
    unsigned char* s_alive = (unsigned char*)(smem + 7168);  // 8192

    int c = blk;
    int cnt = counts[c * CNT_STRIDE];
    if (cnt > CAP) cnt = CAP;

    const uint2* cl = cands + (size_t)c * CAP;

    // phase 1: histogram on score bits (scores in [0.6, 1.0])
    if (tid < NB) s_hist[tid] = 0;
    if (tid == 0) s_m = 0;
    __syncthreads();

    for (int e = tid; e < cnt; e += DT) {
        unsigned sc = cl[e].x;                       // >= 0x3F19999A (0.6f)
        atomicAdd(&s_hist[(sc - 0x3F199999u) >> 15], 1);
    }
    __syncthreads();

    if (tid < 64) {
        // wave 0: tau = max bucket with cum-from-top >= TARGET (exact)
        unsigned acc = 0;
        bool found = false;
        for (int ch = NB / 64 - 1; ch >= 0 && !found; --ch) {
            unsigned h = (unsigned)s_hist[ch * 64 + tid];
            unsigned incl = wave_incl_scan(h);
            unsigned total = (unsigned)__builtin_amdgcn_readlane((int)incl, 63);
            bool ok = acc + (total - incl + h) >= (unsigned)TARGET;
            unsigned long long mk = __ballot(ok);
            if (mk) {
                if (tid == 0) s_tau = ch * 64 + (63 - __builtin_clzll(mk));
                found = true;
            }
            acc += total;
        }
        if (!found && tid == 0) s_tau = 0;   // take all (total < TARGET)
    }
    __syncthreads();

    int tau = s_tau;
    for (int e = tid; e < cnt; e += DT) {
        uint2 v = cl[e];
        if ((int)((v.x - 0x3F199999u) >> 15) >= tau) {
            int p = atomicAdd(&s_m, 1);
            if (p < SCAP) {
                s_csc[p] = v.x;
                s_cix[p] = v.y;
                s_cbox[p] = boxes[v.y];
            }
        }
    }
    __syncthreads();

    if (tid >= 64) return;          // only wave 0 continues (no more barriers)

    int lane = tid;
    int m = s_m;
    bool need_fb = (m > SCAP);
    if (m > SCAP) m = SCAP;

    float* ob  = out;             // 1600 boxes * 4
    float* os  = out + 6400;      // 1600 scores
    float* ocl = out + 8000;      // 1600 classes (as float)

    int sel = 0;

    if (!need_fb) {
        unsigned scu[4], ixu[4];
        float4 bx[4];
        float  ar[4];
#pragma unroll
        for (int k = 0; k < 4; ++k) {
            int e = lane + k * 64;
            scu[k] = 0u; ixu[k] = 0xFFFFFFFFu;
            bx[k] = make_float4(0.f, 0.f, 0.f, 0.f);
            ar[k] = 0.f;
            if (e < m) {
                scu[k] = s_csc[e];
                ixu[k] = s_cix[e];
                bx[k] = s_cbox[e];
                ar[k] = (bx[k].z - bx[k].x) * (bx[k].w - bx[k].y);
            }
        }

        for (; sel < MAXB; ++sel) {
            unsigned lm = 0u;
#pragma unroll
            for (int k = 0; k < 4; ++k) lm = lm > scu[k] ? lm : scu[k];
            unsigned smax = wave_max_bcast(lm);
            if (smax == 0u) {
                if (m < cnt) need_fb = true;   // compact list exhausted early
                break;
            }
            unsigned li = 0xFFFFFFFFu;
#pragma unroll
            for (int k = 0; k < 4; ++k)
                if (scu[k] == smax && ixu[k] < li) li = ixu[k];
            unsigned bidx = wave_min_bcast(li);

            bool has = false;
            float4 ob_ = make_float4(0.f, 0.f, 0.f, 0.f);
#pragma unroll
            for (int k = 0; k < 4; ++k)
                if (scu[k] == smax && ixu[k] == bidx) { ob_ = bx[k]; has = true; }
            unsigned long long mk = __ballot(has);
            int src = __ffsll((long long)mk) - 1;
            float4 sb;
            sb.x = __int_as_float(__builtin_amdgcn_readlane(__float_as_int(ob_.x), src));
            sb.y = __int_as_float(__builtin_amdgcn_readlane(__float_as_int(ob_.y), src));
            sb.z = __int_as_float(__builtin_amdgcn_readlane(__float_as_int(ob_.z), src));
            sb.w = __int_as_float(__builtin_amdgcn_readlane(__float_as_int(ob_.w), src));
            float area_s = (sb.z - sb.x) * (sb.w - sb.y);

            if (lane == 0) {
                int o = c * MAXB + sel;
                ob[o * 4 + 0] = sb.x; ob[o * 4 + 1] = sb.y;
                ob[o * 4 + 2] = sb.z; ob[o * 4 + 3] = sb.w;
                os[o]  = __uint_as_float(smax);
                ocl[o] = (float)c;
            }

#pragma unroll
            for (int k = 0; k < 4; ++k) {
                if (scu[k] != 0u) {
                    float y1 = fmaxf(sb.x, bx[k].x);
                    float x1 = fmaxf(sb.y, bx[k].y);
                    float y2 = fminf(sb.z, bx[k].z);
                    float x2 = fminf(sb.w, bx[k].w);
                    float inter = fmaxf(y2 - y1, 0.f) * fmaxf(x2 - x1, 0.f);
                    float un = area_s + ar[k] - inter;
                    float iou = (un > 0.f) ? (inter / un) : 0.f;
                    if (iou > 0.5f || ixu[k] == bidx) scu[k] = 0u;
                }
            }
        }
    }

    if (need_fb) {
        // exact full-list greedy NMS from scratch (statistically never taken)
        for (int e = lane; e < cnt; e += 64) s_alive[e] = 1;
        sel = 0;
        for (; sel < MAXB; ++sel) {
            unsigned bs = 0u, bi = 0xFFFFFFFFu;
            for (int e = lane; e < cnt; e += 64) {
                if (s_alive[e]) {
                    uint2 v = cl[e];
                    if (v.x > bs || (v.x == bs && v.y < bi)) { bs = v.x; bi = v.y; }
                }
            }
            unsigned smax = wave_max_bcast(bs);
            if (smax == 0u) break;
            unsigned li = (bs == smax) ? bi : 0xFFFFFFFFu;
            unsigned bidx = wave_min_bcast(li);

            float4 sb = boxes[bidx];
            float area_s = (sb.z - sb.x) * (sb.w - sb.y);

            if (lane == 0) {
                int o = c * MAXB + sel;
                ob[o * 4 + 0] = sb.x; ob[o * 4 + 1] = sb.y;
                ob[o * 4 + 2] = sb.z; ob[o * 4 + 3] = sb.w;
                os[o]  = __uint_as_float(smax);
                ocl[o] = (float)c;
            }

            for (int e = lane; e < cnt; e += 64) {
                if (s_alive[e]) {
                    uint2 v = cl[e];
                    float4 cb = boxes[v.y];
                    float y1 = fmaxf(sb.x, cb.x);
                    float x1 = fmaxf(sb.y, cb.y);
                    float y2 = fminf(sb.z, cb.z);
                    float x2 = fminf(sb.w, cb.w);
                    float inter = fmaxf(y2 - y1, 0.f) * fmaxf(x2 - x1, 0.f);
                    float area_c = (cb.z - cb.x) * (cb.w - cb.y);
                    float un = area_s + area_c - inter;
                    float iou = (un > 0.f) ? (inter / un) : 0.f;
                    if (iou > 0.5f || v.y == bidx) s_alive[e] = 0;
                }
            }
        }
    }

    // invalid slots: zero boxes/scores, class = -1 (lane-parallel)
    for (int q = sel + lane; q < MAXB; q += 64) {
        int o = c * MAXB + q;
        ob[o * 4 + 0] = 0.0f; ob[o * 4 + 1] = 0.0f;
        ob[o * 4 + 2] = 0.0f; ob[o * 4 + 3] = 0.0f;
        os[o]  = 0.0f;
        ocl[o] = -1.0f;
    }
}

extern "C" void kernel_launch(void* const* d_in, const int* in_sizes, int n_in,
                              void* d_out, int out_size, void* d_ws, size_t ws_size,
                              hipStream_t stream) {
    const float* feats0 = (const float*)d_in[0];
    const float* feats1 = (const float*)d_in[1];
    float* out = (float*)d_out;

    char* ws = (char*)d_ws;
    float4* boxes  = (float4*)ws;                      // NTOT*16B = 2,211,840
    int*    counts = (int*)(ws + 2211840);             // 80*16*4B
    uint2*  cands  = (uint2*)(ws + 2211840 + 8192);    // 80*CAP*8B = 5.24MB

    void* kargs[] = {(void*)&feats0, (void*)&feats1, (void*)&boxes,
                     (void*)&cands, (void*)&counts, (void*)&out};
    hipLaunchCooperativeKernel((const void*)fused_kernel, dim3(NBLK), dim3(DT),
                               kargs, 0, stream);
}

// Round 9
// 51.368 us; speedup vs baseline: 2.1999x; 2.1999x over previous
//
#include <hip/hip_runtime.h>

#define NCLS 80
#define MAXB 20
#define N0 27648     // 96*96*3
#define N1 110592    // 192*192*3
#define NTOT (N0 + N1)
#define CAP 8192       // per-class candidate capacity in workspace
#define DT 512         // decode block size
#define DSTAGE 3072    // per-block candidate staging (expected ~1122, +59 sigma)
#define CNT_STRIDE 16  // pad class counters to one 64B line each
#define NMS_T 1024
#define NB 256         // score histogram buckets ((bits-0.6f)>>15, max 204)
#define TARGET 128     // top-k cut for fast NMS path
#define SCAP 256       // compact-list capacity (4 slots/lane in wave 0)

__device__ __forceinline__ float sigf(float x) {
    return 1.0f / (1.0f + expf(-x));
}

// ---- DPP wave64 primitives (proven exact rounds 5-8, absmax 0) ----
__device__ __forceinline__ unsigned wave_max_bcast(unsigned x) {
    unsigned t;
    t = (unsigned)__builtin_amdgcn_update_dpp((int)x, (int)x, 0x111, 0xF, 0xF, false); x = x > t ? x : t;
    t = (unsigned)__builtin_amdgcn_update_dpp((int)x, (int)x, 0x112, 0xF, 0xF, false); x = x > t ? x : t;
    t = (unsigned)__builtin_amdgcn_update_dpp((int)x, (int)x, 0x114, 0xF, 0xF, false); x = x > t ? x : t;
    t = (unsigned)__builtin_amdgcn_update_dpp((int)x, (int)x, 0x118, 0xF, 0xF, false); x = x > t ? x : t;
    t = (unsigned)__builtin_amdgcn_update_dpp((int)x, (int)x, 0x142, 0xF, 0xF, false); x = x > t ? x : t;
    t = (unsigned)__builtin_amdgcn_update_dpp((int)x, (int)x, 0x143, 0xF, 0xF, false); x = x > t ? x : t;
    return (unsigned)__builtin_amdgcn_readlane((int)x, 63);
}

__device__ __forceinline__ unsigned wave_min_bcast(unsigned x) {
    unsigned t;
    t = (unsigned)__builtin_amdgcn_update_dpp((int)x, (int)x, 0x111, 0xF, 0xF, false); x = x < t ? x : t;
    t = (unsigned)__builtin_amdgcn_update_dpp((int)x, (int)x, 0x112, 0xF, 0xF, false); x = x < t ? x : t;
    t = (unsigned)__builtin_amdgcn_update_dpp((int)x, (int)x, 0x114, 0xF, 0xF, false); x = x < t ? x : t;
    t = (unsigned)__builtin_amdgcn_update_dpp((int)x, (int)x, 0x118, 0xF, 0xF, false); x = x < t ? x : t;
    t = (unsigned)__builtin_amdgcn_update_dpp((int)x, (int)x, 0x142, 0xF, 0xF, false); x = x < t ? x : t;
    t = (unsigned)__builtin_amdgcn_update_dpp((int)x, (int)x, 0x143, 0xF, 0xF, false); x = x < t ? x : t;
    return (unsigned)__builtin_amdgcn_readlane((int)x, 63);
}

// Wave64 inclusive +scan (LLVM AtomicOptimizer idiom).
__device__ __forceinline__ unsigned wave_incl_scan(unsigned x) {
    x += (unsigned)__builtin_amdgcn_update_dpp(0, (int)x, 0x111, 0xF, 0xF, false);
    x += (unsigned)__builtin_amdgcn_update_dpp(0, (int)x, 0x112, 0xF, 0xF, false);
    x += (unsigned)__builtin_amdgcn_update_dpp(0, (int)x, 0x114, 0xF, 0xF, false);
    x += (unsigned)__builtin_amdgcn_update_dpp(0, (int)x, 0x118, 0xF, 0xF, false);
    x += (unsigned)__builtin_amdgcn_update_dpp(0, (int)x, 0x142, 0xA, 0xF, false);
    x += (unsigned)__builtin_amdgcn_update_dpp(0, (int)x, 0x143, 0xC, 0xF, false);
    return x;
}

// r7 decode with phase-2 sweep eliminated: per-class local position (lpos) is
// taken at emission time (second LDS atomic) and stored in a u16 side-array,
// so the pipeline is: gate -> boxes -> emit(+count) -> reserve -> scatter
// (4 barriers instead of 5, one fewer full staging sweep). Final global slot
// base[c]+lpos is a permutation of the same slice; NMS result is invariant
// to candidate order via the idx tie-break.
__global__ __launch_bounds__(DT) void decode_kernel(
    const float* __restrict__ feats0, const float* __restrict__ feats1,
    float4* __restrict__ boxes, uint2* __restrict__ cands,
    int* __restrict__ counts)
{
    __shared__ unsigned p_gi[DT];
    __shared__ float    p_conf[DT];
    __shared__ int s_npass;
    __shared__ float    s_esc[DSTAGE];
    __shared__ unsigned s_ent[DSTAGE];       // gi | (class<<18)
    __shared__ unsigned short s_lp[DSTAGE];  // per-class local position
    __shared__ int s_n;
    __shared__ int s_cnt[NCLS];
    __shared__ int s_base[NCLS];

    int tid = threadIdx.x;
    if (tid == 0) { s_npass = 0; s_n = 0; }
    for (int c = tid; c < NCLS; c += DT) s_cnt[c] = 0;
    __syncthreads();

    const float* feats;
    int S, base, i;
    float aw0, ah0, aw1, ah1, aw2, ah2;
    if (blockIdx.x < N0 / DT) {
        feats = feats0; S = 96; base = 0;
        i = blockIdx.x * DT + tid;
        aw0 = 81.0f;  ah0 = 82.0f;  aw1 = 135.0f; ah1 = 169.0f; aw2 = 344.0f; ah2 = 319.0f;
    } else {
        feats = feats1; S = 192; base = N0;
        i = (blockIdx.x - N0 / DT) * DT + tid;
        aw0 = 23.0f;  ah0 = 27.0f;  aw1 = 37.0f;  ah1 = 58.0f;  aw2 = 81.0f;  ah2 = 82.0f;
    }

    // ---- phase 0: conf gate (only f[4] needed) ----
    float sconf = sigf(feats[(size_t)i * 85 + 4]);
    if (sconf >= 0.6f) {   // sconf < 0.6 => all class scores < 0.6 (exact)
        int sl = atomicAdd(&s_npass, 1);   // <= DT
        p_gi[sl] = (unsigned)(base + i);
        p_conf[sl] = sconf;
    }
    __syncthreads();

    int npass = s_npass;

    // ---- phase 0b: box decode + write for pass anchors only ----
    for (int e = tid; e < npass; e += DT) {
        int il = (int)p_gi[e] - base;
        int a = il % 3;
        int cell = il / 3;
        int gx = cell % S;
        int gy = cell / S;
        const float* f = feats + (size_t)il * 85;
        float tx = f[0], ty = f[1], tw = f[2], th = f[3];

        float Sf = (float)S;
        float inpf = Sf * 32.0f;
        float aw = (a == 0) ? aw0 : ((a == 1) ? aw1 : aw2);
        float ah = (a == 0) ? ah0 : ((a == 1) ? ah1 : ah2);

        float x = (sigf(tx) + (float)gx) / Sf;
        float y = (sigf(ty) + (float)gy) / Sf;
        float w = expf(tw) * aw / inpf;
        float h = expf(th) * ah / inpf;

        // yolo_correct_boxes: letterbox constants identical for both layers
        const float OFF = 0.21875f;
        const float SC  = 3072.0f / 1728.0f;
        float yy = (y - OFF) * SC;
        float hh = h * SC;

        boxes[p_gi[e]] = make_float4((yy - hh * 0.5f) * 1080.0f,
                                     (x  - w  * 0.5f) * 1920.0f,
                                     (yy + hh * 0.5f) * 1080.0f,
                                     (x  + w  * 0.5f) * 1920.0f);
    }

    // ---- phase 1: dense (pass-anchor, class) emission, counting inline ----
    int tot = npass * NCLS;
    for (int wk = tid; wk < tot; wk += DT) {
        int sl = wk / NCLS;
        int c  = wk - sl * NCLS;
        float pv = feats[(size_t)(p_gi[sl] - (unsigned)base) * 85 + 5 + c];
        float s = p_conf[sl] * sigf(pv);
        if (s >= 0.6f) {
            int e = atomicAdd(&s_n, 1);
            int lp = atomicAdd(&s_cnt[c], 1);
            if (e < DSTAGE) {
                s_esc[e] = s;
                s_ent[e] = p_gi[sl] | ((unsigned)c << 18);
                s_lp[e] = (unsigned short)lp;
            }
        }
    }
    __syncthreads();

    int n = s_n < DSTAGE ? s_n : DSTAGE;

    // ---- phase 2: one reserve atomic per (block,class), padded lines ----
    for (int c = tid; c < NCLS; c += DT) {
        int k = s_cnt[c];
        s_base[c] = (k > 0) ? atomicAdd(&counts[c * CNT_STRIDE], k) : 0;
    }
    __syncthreads();

    // ---- phase 3: scatter into reserved slices (no atomics) ----
    for (int e = tid; e < n; e += DT) {
        unsigned ent = s_ent[e];
        int c = ent >> 18;
        int pos = s_base[c] + (int)s_lp[e];
        if (pos < CAP)
            cands[(size_t)c * CAP + pos] =
                make_uint2(__float_as_uint(s_esc[e]), ent & 0x3FFFFu);
    }
}

// One block per class (byte-identical to round 7, proven 51.5us / absmax 0).
// Phase 1 (16 waves): 256-bucket score histogram -> wave-0 DPP-scan finds the
// exact TARGET-th threshold bucket -> compact all cands >= bucket floor.
// Phase 2 (wave 0, barrier-free): register-resident greedy NMS (DPP argmax,
// ballot+readlane box broadcast, 4-slot suppression). Exact full-list
// fallback if the compact list overflows or exhausts early.
__global__ __launch_bounds__(NMS_T) void nms_kernel(
    const float4* __restrict__ boxes, const uint2* __restrict__ cands,
    const int* __restrict__ counts, float* __restrict__ out)
{
    __shared__ int s_hist[NB];
    __shared__ int s_tau;
    __shared__ int s_m;
    __shared__ float4   s_cbox[SCAP];
    __shared__ unsigned s_csc[SCAP];
    __shared__ unsigned s_cix[SCAP];
    __shared__ unsigned char s_alive[CAP];   // fallback only

    int c = blockIdx.x;
    int tid = threadIdx.x;

    int cnt = counts[c * CNT_STRIDE];
    if (cnt > CAP) cnt = CAP;

    const uint2* cl = cands + (size_t)c * CAP;

    // ---- phase 1: histogram on score bits (scores in [0.6, 1.0]) ----
    if (tid < NB) s_hist[tid] = 0;
    if (tid == 0) s_m = 0;
    __syncthreads();

    for (int e = tid; e < cnt; e += NMS_T) {
        unsigned sc = cl[e].x;                       // >= 0x3F19999A (0.6f)
        atomicAdd(&s_hist[(sc - 0x3F199999u) >> 15], 1);
    }
    __syncthreads();

    if (tid < 64) {
        // wave 0: tau = max bucket with cum-from-top >= TARGET (exact)
        unsigned acc = 0;
        bool found = false;
        for (int ch = NB / 64 - 1; ch >= 0 && !found; --ch) {
            unsigned h = (unsigned)s_hist[ch * 64 + tid];
            unsigned incl = wave_incl_scan(h);
            unsigned total = (unsigned)__builtin_amdgcn_readlane((int)incl, 63);
            bool ok = acc + (total - incl + h) >= (unsigned)TARGET;
            unsigned long long mk = __ballot(ok);
            if (mk) {
                if (tid == 0) s_tau = ch * 64 + (63 - __builtin_clzll(mk));
                found = true;
            }
            acc += total;
        }
        if (!found && tid == 0) s_tau = 0;   // take all (total < TARGET)
    }
    __syncthreads();

    int tau = s_tau;
    for (int e = tid; e < cnt; e += NMS_T) {
        uint2 v = cl[e];
        if ((int)((v.x - 0x3F199999u) >> 15) >= tau) {
            int p = atomicAdd(&s_m, 1);
            if (p < SCAP) {
                s_csc[p] = v.x;
                s_cix[p] = v.y;
                s_cbox[p] = boxes[v.y];
            }
        }
    }
    __syncthreads();

    if (tid >= 64) return;          // only wave 0 continues (no more barriers)

    int lane = tid;
    int m = s_m;
    bool need_fb = (m > SCAP);
    if (m > SCAP) m = SCAP;

    float* ob  = out;             // 1600 boxes * 4
    float* os  = out + 6400;      // 1600 scores
    float* ocl = out + 8000;      // 1600 classes (as float)

    int sel = 0;

    if (!need_fb) {
        unsigned scu[4], ixu[4];
        float4 bx[4];
        float  ar[4];
#pragma unroll
        for (int k = 0; k < 4; ++k) {
            int e = lane + k * 64;
            scu[k] = 0u; ixu[k] = 0xFFFFFFFFu;
            bx[k] = make_float4(0.f, 0.f, 0.f, 0.f);
            ar[k] = 0.f;
            if (e < m) {
                scu[k] = s_csc[e];
                ixu[k] = s_cix[e];
                bx[k] = s_cbox[e];
                ar[k] = (bx[k].z - bx[k].x) * (bx[k].w - bx[k].y);
            }
        }

        for (; sel < MAXB; ++sel) {
            unsigned lm = 0u;
#pragma unroll
            for (int k = 0; k < 4; ++k) lm = lm > scu[k] ? lm : scu[k];
            unsigned smax = wave_max_bcast(lm);
            if (smax == 0u) {
                if (m < cnt) need_fb = true;   // compact list exhausted early
                break;
            }
            unsigned li = 0xFFFFFFFFu;
#pragma unroll
            for (int k = 0; k < 4; ++k)
                if (scu[k] == smax && ixu[k] < li) li = ixu[k];
            unsigned bidx = wave_min_bcast(li);

            bool has = false;
            float4 ob_ = make_float4(0.f, 0.f, 0.f, 0.f);
#pragma unroll
            for (int k = 0; k < 4; ++k)
                if (scu[k] == smax && ixu[k] == bidx) { ob_ = bx[k]; has = true; }
            unsigned long long mk = __ballot(has);
            int src = __ffsll((long long)mk) - 1;
            float4 sb;
            sb.x = __int_as_float(__builtin_amdgcn_readlane(__float_as_int(ob_.x), src));
            sb.y = __int_as_float(__builtin_amdgcn_readlane(__float_as_int(ob_.y), src));
            sb.z = __int_as_float(__builtin_amdgcn_readlane(__float_as_int(ob_.z), src));
            sb.w = __int_as_float(__builtin_amdgcn_readlane(__float_as_int(ob_.w), src));
            float area_s = (sb.z - sb.x) * (sb.w - sb.y);

            if (lane == 0) {
                int o = c * MAXB + sel;
                ob[o * 4 + 0] = sb.x; ob[o * 4 + 1] = sb.y;
                ob[o * 4 + 2] = sb.z; ob[o * 4 + 3] = sb.w;
                os[o]  = __uint_as_float(smax);
                ocl[o] = (float)c;
            }

#pragma unroll
            for (int k = 0; k < 4; ++k) {
                if (scu[k] != 0u) {
                    float y1 = fmaxf(sb.x, bx[k].x);
                    float x1 = fmaxf(sb.y, bx[k].y);
                    float y2 = fminf(sb.z, bx[k].z);
                    float x2 = fminf(sb.w, bx[k].w);
                    float inter = fmaxf(y2 - y1, 0.f) * fmaxf(x2 - x1, 0.f);
                    float un = area_s + ar[k] - inter;
                    float iou = (un > 0.f) ? (inter / un) : 0.f;
                    if (iou > 0.5f || ixu[k] == bidx) scu[k] = 0u;
                }
            }
        }
    }

    if (need_fb) {
        // exact full-list greedy NMS from scratch (statistically never taken)
        for (int e = lane; e < cnt; e += 64) s_alive[e] = 1;
        sel = 0;
        for (; sel < MAXB; ++sel) {
            unsigned bs = 0u, bi = 0xFFFFFFFFu;
            for (int e = lane; e < cnt; e += 64) {
                if (s_alive[e]) {
                    uint2 v = cl[e];
                    if (v.x > bs || (v.x == bs && v.y < bi)) { bs = v.x; bi = v.y; }
                }
            }
            unsigned smax = wave_max_bcast(bs);
            if (smax == 0u) break;
            unsigned li = (bs == smax) ? bi : 0xFFFFFFFFu;
            unsigned bidx = wave_min_bcast(li);

            float4 sb = boxes[bidx];
            float area_s = (sb.z - sb.x) * (sb.w - sb.y);

            if (lane == 0) {
                int o = c * MAXB + sel;
                ob[o * 4 + 0] = sb.x; ob[o * 4 + 1] = sb.y;
                ob[o * 4 + 2] = sb.z; ob[o * 4 + 3] = sb.w;
                os[o]  = __uint_as_float(smax);
                ocl[o] = (float)c;
            }

            for (int e = lane; e < cnt; e += 64) {
                if (s_alive[e]) {
                    uint2 v = cl[e];
                    float4 cb = boxes[v.y];
                    float y1 = fmaxf(sb.x, cb.x);
                    float x1 = fmaxf(sb.y, cb.y);
                    float y2 = fminf(sb.z, cb.z);
                    float x2 = fminf(sb.w, cb.w);
                    float inter = fmaxf(y2 - y1, 0.f) * fmaxf(x2 - x1, 0.f);
                    float area_c = (cb.z - cb.x) * (cb.w - cb.y);
                    float un = area_s + area_c - inter;
                    float iou = (un > 0.f) ? (inter / un) : 0.f;
                    if (iou > 0.5f || v.y == bidx) s_alive[e] = 0;
                }
            }
        }
    }

    // invalid slots: zero boxes/scores, class = -1 (lane-parallel)
    for (int q = sel + lane; q < MAXB; q += 64) {
        int o = c * MAXB + q;
        ob[o * 4 + 0] = 0.0f; ob[o * 4 + 1] = 0.0f;
        ob[o * 4 + 2] = 0.0f; ob[o * 4 + 3] = 0.0f;
        os[o]  = 0.0f;
        ocl[o] = -1.0f;
    }
}

extern "C" void kernel_launch(void* const* d_in, const int* in_sizes, int n_in,
                              void* d_out, int out_size, void* d_ws, size_t ws_size,
                              hipStream_t stream) {
    const float* feats0 = (const float*)d_in[0];
    const float* feats1 = (const float*)d_in[1];
    float* out = (float*)d_out;

    char* ws = (char*)d_ws;
    float4* boxes  = (float4*)ws;                      // NTOT*16B = 2,211,840
    int*    counts = (int*)(ws + 2211840);             // 80*16*4B
    uint2*  cands  = (uint2*)(ws + 2211840 + 8192);    // 80*CAP*8B = 5.24MB

    hipMemsetAsync(counts, 0, NCLS * CNT_STRIDE * sizeof(int), stream);

    decode_kernel<<<NTOT / DT, DT, 0, stream>>>(feats0, feats1, boxes, cands, counts);

    nms_kernel<<<NCLS, NMS_T, 0, stream>>>(boxes, cands, counts, out);
}